// Round 5
// baseline (212.463 us; speedup 1.0000x reference)
//
#include <hip/hip_runtime.h>
#include <math.h>

#define THREADS 256   // 8 threads per token-slot; thread = one expert group, 2 tokens
#define TPB 64        // tokens per block (2 per thread)
#define NEXP 256
// integer margins in 2^-22 quanta:
#define Q_EPS  12u    // single-score margin (~2.9e-6; pipeline err <= ~5 quanta/side)
#define QG_EPS 28u    // group-sum margin   (~6.7e-6; >= old 4e-6 float margin + quant err)

// ---- fast f32 sigmoid: hw v_exp_f32 + fast divide ----
__device__ __forceinline__ float fsigmoid(float x) {
    float e = __expf(-x);
    return __fdividef(1.0f, 1.0f + e);
}

// ---- cheap near-exact f64 sigmoid (rare paths only): Taylor exp + NR division ----
__device__ __forceinline__ double dsigmoid(float xf) {
    xf = fminf(fmaxf(xf, -500.0f), 500.0f);
    double x = (double)xf;
    double t = x * -1.4426950408889634074;           // -x*log2(e)
    double n = floor(t + 0.5);
    int ni = (int)n;
    double u = (t - n) * 0.69314718055994530942;
    double pp = 2.08767569878680990e-9;
    pp = fma(pp, u, 2.50521083854417188e-8);
    pp = fma(pp, u, 2.75573192239858907e-7);
    pp = fma(pp, u, 2.75573192239858883e-6);
    pp = fma(pp, u, 2.48015873015873016e-5);
    pp = fma(pp, u, 1.98412698412698413e-4);
    pp = fma(pp, u, 1.38888888888888889e-3);
    pp = fma(pp, u, 8.33333333333333333e-3);
    pp = fma(pp, u, 4.16666666666666667e-2);
    pp = fma(pp, u, 1.66666666666666667e-1);
    pp = fma(pp, u, 0.5);
    pp = fma(pp, u, 1.0);
    pp = fma(pp, u, 1.0);
    double sc = __longlong_as_double((long long)(1023 + ni) << 52);
    double e = pp * sc;                              // exp(-x)
    double w = 1.0 + e;
    double y = (double)__fdividef(1.0f, (float)w);
    y = fma(y, fma(-w, y, 1.0), y);
    y = fma(y, fma(-w, y, 1.0), y);
    return y;
}

// f64 8-deep sorted insert (cold path)
#define DINS(cc, ee) do {                                                \
    double _d=(cc); int _e=(ee);                                         \
    if (_d > s7) {                                                       \
        bool _b0=_d>s0,_b1=_d>s1,_b2=_d>s2,_b3=_d>s3,_b4=_d>s4,          \
             _b5=_d>s5,_b6=_d>s6;                                        \
        s7=_b6?s6:_d;           c7=_b6?c6:_e;                            \
        s6=_b5?s5:(_b6?_d:s6);  c6=_b5?c5:(_b6?_e:c6);                   \
        s5=_b4?s4:(_b5?_d:s5);  c5=_b4?c4:(_b5?_e:c5);                   \
        s4=_b3?s3:(_b4?_d:s4);  c4=_b3?c3:(_b4?_e:c4);                   \
        s3=_b2?s2:(_b3?_d:s3);  c3=_b2?c2:(_b3?_e:c3);                   \
        s2=_b1?s1:(_b2?_d:s2);  c2=_b1?c1:(_b2?_e:c2);                   \
        s1=_b0?s0:(_b1?_d:s1);  c1=_b0?c0:(_b1?_e:c1);                   \
        s0=_b0?_d:s0;           c0=_b0?_e:c0;                            \
    } } while (0)

// ======== packed sort keys (validated rounds 3-4) ========
// key = (u32(c*2^22 + 2^21) << 8) + (255 - expert_id)
// u32 desc order == (score desc, id asc) exactly; keys unique (ids unique).
// Quantum 2.38e-7; any ambiguity within Q_EPS quanta -> exact f64 re-resolve.

// CEU: descending compare-exchange -> v_max_u32 + v_min_u32 (2 VALU)
#define CEU(a, b) do {                                                   \
    unsigned _x=(a), _y=(b);                                             \
    (a) = _x>_y ? _x : _y; (b) = _x>_y ? _y : _x;                        \
} while (0)
// VMU: a := max(a,b) -> v_max_u32 (1 VALU)
#define VMU(a, b) do { (a) = (a)>(b) ? (a) : (b); } while (0)

// Batcher odd-even mergesort network for 8 keys, descending. 19 CE.
#define SORT8U(v0,v1,v2,v3,v4,v5,v6,v7) do {                             \
    CEU(v0,v1); CEU(v2,v3); CEU(v4,v5); CEU(v6,v7);                      \
    CEU(v0,v2); CEU(v1,v3); CEU(v4,v6); CEU(v5,v7);                      \
    CEU(v1,v2); CEU(v5,v6);                                              \
    CEU(v0,v4); CEU(v1,v5); CEU(v2,v6); CEU(v3,v7);                      \
    CEU(v2,v4); CEU(v3,v5);                                              \
    CEU(v1,v2); CEU(v3,v4); CEU(v5,v6);                                  \
} while (0)

// valley (dec-then-inc) 9-seq -> sorted descending. 13 CE. (validated r1-r4)
#define CLEAN9M(a0,a1,a2,a3,a4,a5,a6,a7,a8) do {                         \
    CEU(a0,a8);                                                          \
    CEU(a1,a5); CEU(a2,a6); CEU(a3,a7); CEU(a4,a8);                      \
    CEU(a1,a3); CEU(a2,a4); CEU(a5,a7); CEU(a6,a8);                      \
    CEU(a1,a2); CEU(a3,a4); CEU(a5,a6); CEU(a7,a8);                      \
} while (0)

// Merge my sorted-desc 9-list with xor-partner's via the bitonic identity:
//   t[i] = max(a[i], b[8-i]) is the top-9 multiset, as a valley sequence.
#define XMERGE_U(d) do {                                                 \
    unsigned q0=(unsigned)__shfl_xor((int)m0,d,64),                      \
             q1=(unsigned)__shfl_xor((int)m1,d,64),                      \
             q2=(unsigned)__shfl_xor((int)m2,d,64),                      \
             q3=(unsigned)__shfl_xor((int)m3,d,64),                      \
             q4=(unsigned)__shfl_xor((int)m4,d,64),                      \
             q5=(unsigned)__shfl_xor((int)m5,d,64),                      \
             q6=(unsigned)__shfl_xor((int)m6,d,64),                      \
             q7=(unsigned)__shfl_xor((int)m7,d,64),                      \
             q8=(unsigned)__shfl_xor((int)m8,d,64);                      \
    VMU(m0,q8); VMU(m1,q7); VMU(m2,q6); VMU(m3,q5); VMU(m4,q4);          \
    VMU(m5,q3); VMU(m6,q2); VMU(m7,q1); VMU(m8,q0);                      \
    CLEAN9M(m0,m1,m2,m3,m4,m5,m6,m7,m8);                                 \
} while (0)

// (256,4): VGPR cap 128. Peak live ~95 (Bq 32 + kk 32 + sort temps).
// Spill canary: WRITE_SIZE must stay ~8.3 MB (round-2 spill showed 41 MB).
__global__ __launch_bounds__(THREADS, 4)
void noauxtc_router_kernel(const float* __restrict__ logits,
                           const float* __restrict__ bias,
                           float* __restrict__ out,   // [T*8] weights, [T*8] ids-as-f32
                           int T)
{
    const int tid   = threadIdx.x;
    const int h     = tid & 7;            // owned group (experts 32h..32h+31)
    const int p     = tid >> 3;           // token-slot-in-block (0..31)
    const int tok0  = blockIdx.x * TPB;
    const int lane  = tid & 63;
    const int base  = lane & 56;          // first lane of this token's octet

    // ---- own-group bias pack-constants from global (1 KB region, L1-hot) ----
    // Bq[e] = bias[e]*2^22 + 2^21 so pack = u32(fma(sig, 2^22, Bq)) -- one fma/expert.
    const float4* bg4 = (const float4*)bias + h * 8;
    float4 Bq[8];
    #pragma unroll
    for (int j = 0; j < 8; ++j) {
        float4 b = bg4[j];
        Bq[j].x = fmaf(b.x, 4194304.0f, 2097152.0f);
        Bq[j].y = fmaf(b.y, 4194304.0f, 2097152.0f);
        Bq[j].z = fmaf(b.z, 4194304.0f, 2097152.0f);
        Bq[j].w = fmaf(b.w, 4194304.0f, 2097152.0f);
    }

    // ---- full per-token pipeline: barrier-free, LDS-free ----
    auto process = [&](int token) {
        // own group's 32 logits: one 128B line, 8x b128
        const float4* lg4 = (const float4*)logits + (size_t)token * 64 + h * 8;
        float4 st[8];
        #pragma unroll
        for (int k = 0; k < 8; ++k) st[k] = lg4[k];

        // pack keys
        unsigned kk[32];
        #pragma unroll
        for (int q = 0; q < 8; ++q) {
            float4 x = st[q], B = Bq[q];
            int idf = 255 - (h * 32 + q * 4);
            kk[q*4+0] = ((unsigned)fmaf(fsigmoid(x.x), 4194304.0f, B.x) << 8) + (unsigned)(idf    );
            kk[q*4+1] = ((unsigned)fmaf(fsigmoid(x.y), 4194304.0f, B.y) << 8) + (unsigned)(idf - 1);
            kk[q*4+2] = ((unsigned)fmaf(fsigmoid(x.z), 4194304.0f, B.z) << 8) + (unsigned)(idf - 2);
            kk[q*4+3] = ((unsigned)fmaf(fsigmoid(x.w), 4194304.0f, B.w) << 8) + (unsigned)(idf - 3);
        }

        // own-group sorted top-9 of 32 (4x sort8 -> valleys)
        SORT8U(kk[0], kk[1], kk[2], kk[3], kk[4], kk[5], kk[6], kk[7]);
        SORT8U(kk[8], kk[9], kk[10],kk[11],kk[12],kk[13],kk[14],kk[15]);
        SORT8U(kk[16],kk[17],kk[18],kk[19],kk[20],kk[21],kk[22],kk[23]);
        SORT8U(kk[24],kk[25],kk[26],kk[27],kk[28],kk[29],kk[30],kk[31]);

        unsigned t0=kk[0],t1=kk[1],t2=kk[2],t3=kk[3],t4=kk[4],t5=kk[5],t6=kk[6],t7=kk[7],t8=0u;
        VMU(t1,kk[15]); VMU(t2,kk[14]); VMU(t3,kk[13]); VMU(t4,kk[12]);
        VMU(t5,kk[11]); VMU(t6,kk[10]); VMU(t7,kk[9]);  VMU(t8,kk[8]);
        CLEAN9M(t0,t1,t2,t3,t4,t5,t6,t7,t8);

        unsigned u0=kk[16],u1=kk[17],u2=kk[18],u3=kk[19],u4=kk[20],u5=kk[21],u6=kk[22],u7=kk[23],u8=0u;
        VMU(u1,kk[31]); VMU(u2,kk[30]); VMU(u3,kk[29]); VMU(u4,kk[28]);
        VMU(u5,kk[27]); VMU(u6,kk[26]); VMU(u7,kk[25]); VMU(u8,kk[24]);
        CLEAN9M(u0,u1,u2,u3,u4,u5,u6,u7,u8);

        unsigned m0=t0,m1=t1,m2=t2,m3=t3,m4=t4,m5=t5,m6=t6,m7=t7,m8=t8;
        VMU(m0,u8); VMU(m1,u7); VMU(m2,u6); VMU(m3,u5); VMU(m4,u4);
        VMU(m5,u3); VMU(m6,u2); VMU(m7,u1); VMU(m8,u0);
        CLEAN9M(m0,m1,m2,m3,m4,m5,m6,m7,m8);

        // ---- group selection: packed group keys + SORT8 ----
        unsigned gq   = (m0 >> 8) + (m1 >> 8);            // top-2 sum, < 2^24
        unsigned gkey = (gq << 3) + (unsigned)(7 - h);    // (score desc, group id asc)

        unsigned gk0 = (unsigned)__shfl((int)gkey, base + 0, 64);
        unsigned gk1 = (unsigned)__shfl((int)gkey, base + 1, 64);
        unsigned gk2 = (unsigned)__shfl((int)gkey, base + 2, 64);
        unsigned gk3 = (unsigned)__shfl((int)gkey, base + 3, 64);
        unsigned gk4 = (unsigned)__shfl((int)gkey, base + 4, 64);
        unsigned gk5 = (unsigned)__shfl((int)gkey, base + 5, 64);
        unsigned gk6 = (unsigned)__shfl((int)gkey, base + 6, 64);
        unsigned gk7 = (unsigned)__shfl((int)gkey, base + 7, 64);
        SORT8U(gk0,gk1,gk2,gk3,gk4,gk5,gk6,gk7);

        int selmask = (1 << ((gk0 & 7u) ^ 7u)) | (1 << ((gk1 & 7u) ^ 7u)) |
                      (1 << ((gk2 & 7u) ^ 7u)) | (1 << ((gk3 & 7u) ^ 7u));

        // ---- flagA: ambiguous 4th vs 5th group -> pure-f64 re-rank (cold) ----
        if (__builtin_expect((gk3 >> 3) - (gk4 >> 3) < QG_EPS, 0)) {
            double a1 = -1e300, a2 = -1e300;
            const float* lgp = logits + (size_t)token * 256 + h * 32;
            const float* bp  = bias + h * 32;
            #pragma unroll 1
            for (int k = 0; k < 32; ++k) {
                double c = dsigmoid(lgp[k]) + (double)bp[k];
                a2 = fmax(a2, fmin(a1, c)); a1 = fmax(a1, c);
            }
            double gdo = a1 + a2;
            double gd[8];
            #pragma unroll
            for (int g = 0; g < 8; ++g) gd[g] = __shfl(gdo, base + g, 64);
            int sm = 0;
            #pragma unroll
            for (int a = 0; a < 8; ++a) {
                int rk = 0;
                #pragma unroll
                for (int b = 0; b < 8; ++b) {
                    if (b == a) continue;
                    bool beat = (b < a) ? (gd[b] >= gd[a]) : (gd[b] > gd[a]);
                    rk += beat ? 1 : 0;
                }
                sm |= (rk < 4) ? (1 << a) : 0;
            }
            selmask = sm;
        }

        // ---- mask unselected lanes' lists (real keys >> 0) ----
        {
            bool sel = (selmask >> h) & 1;
            m0 = sel ? m0 : 0u; m1 = sel ? m1 : 0u; m2 = sel ? m2 : 0u;
            m3 = sel ? m3 : 0u; m4 = sel ? m4 : 0u; m5 = sel ? m5 : 0u;
            m6 = sel ? m6 : 0u; m7 = sel ? m7 : 0u; m8 = sel ? m8 : 0u;
        }

        // ---- butterfly bitonic merges: 8 lists of 9 -> global top-9 ----
        // symmetric merge: all 8 octet lanes converge to the identical list
        XMERGE_U(1);
        XMERGE_U(2);
        XMERGE_U(4);

        // ---- tail: only the h==0 lane of each octet pays ----
        if (h == 0) {
            unsigned q0=m0>>8, q1=m1>>8, q2=m2>>8, q3=m3>>8, q4=m4>>8,
                     q5=m5>>8, q6=m6>>8, q7=m7>>8, q8=m8>>8;
            int n0=255-(int)(m0&255u), n1=255-(int)(m1&255u), n2=255-(int)(m2&255u),
                n3=255-(int)(m3&255u), n4=255-(int)(m4&255u), n5=255-(int)(m5&255u),
                n6=255-(int)(m6&255u), n7=255-(int)(m7&255u), n8=255-(int)(m8&255u);

            // recovery bias from global (1KB region, L1-hot broadcast)
            float bn0=bias[n0], bn1=bias[n1], bn2=bias[n2], bn3=bias[n3],
                  bn4=bias[n4], bn5=bias[n5], bn6=bias[n6], bn7=bias[n7];

            const float QS = 2.384185791015625e-7f;  // 2^-22
            float w0=fmaf((float)q0,QS,-0.5f)-bn0, w1=fmaf((float)q1,QS,-0.5f)-bn1,
                  w2=fmaf((float)q2,QS,-0.5f)-bn2, w3=fmaf((float)q3,QS,-0.5f)-bn3,
                  w4=fmaf((float)q4,QS,-0.5f)-bn4, w5=fmaf((float)q5,QS,-0.5f)-bn5,
                  w6=fmaf((float)q6,QS,-0.5f)-bn6, w7=fmaf((float)q7,QS,-0.5f)-bn7;
            int o0=n0,o1=n1,o2=n2,o3=n3,o4=n4,o5=n5,o6=n6,o7=n7;

            // q-list non-increasing -> unsigned diffs safe
            bool flagB = ((q0-q1<Q_EPS)|(q1-q2<Q_EPS)|(q2-q3<Q_EPS)|(q3-q4<Q_EPS)|
                          (q4-q5<Q_EPS)|(q5-q6<Q_EPS)|(q6-q7<Q_EPS)|(q7-q8<Q_EPS));
            if (__builtin_expect(flagB, 0)) {
                // f64 re-resolve of the 9 f32-top candidates (cold)
                double s0=-1e300,s1=-1e300,s2=-1e300,s3=-1e300,
                       s4=-1e300,s5=-1e300,s6=-1e300,s7=-1e300;
                int c0=0,c1=0,c2=0,c3=0,c4=0,c5=0,c6=0,c7=0;
                int ci[9] = {n0,n1,n2,n3,n4,n5,n6,n7,n8};
                const float* lgt = logits + (size_t)token * 256;
                #pragma unroll 1
                for (int k = 0; k < 9; ++k) {
                    int e = ci[k];
                    double cs = dsigmoid(lgt[e]) + (double)bias[e];
                    DINS(cs, e);
                }
                w0=(float)(s0-(double)bias[c0]); o0=c0;
                w1=(float)(s1-(double)bias[c1]); o1=c1;
                w2=(float)(s2-(double)bias[c2]); o2=c2;
                w3=(float)(s3-(double)bias[c3]); o3=c3;
                w4=(float)(s4-(double)bias[c4]); o4=c4;
                w5=(float)(s5-(double)bias[c5]); o5=c5;
                w6=(float)(s6-(double)bias[c6]); o6=c6;
                w7=(float)(s7-(double)bias[c7]); o7=c7;
            }

            // epilogue
            float sum = ((w0+w1)+(w2+w3)) + ((w4+w5)+(w6+w7));
            float scl = 2.5f / (sum + 1e-20f);
            float4 oa, ob;
            oa.x=w0*scl; oa.y=w1*scl; oa.z=w2*scl; oa.w=w3*scl;
            ob.x=w4*scl; ob.y=w5*scl; ob.z=w6*scl; ob.w=w7*scl;
            *(float4*)(out + (size_t)token*8)     = oa;
            *(float4*)(out + (size_t)token*8 + 4) = ob;
            float* oid = out + (size_t)T*8;
            float4 ia, ib;
            ia.x=(float)o0; ia.y=(float)o1; ia.z=(float)o2; ia.w=(float)o3;
            ib.x=(float)o4; ib.y=(float)o5; ib.z=(float)o6; ib.w=(float)o7;
            *(float4*)(oid + (size_t)token*8)     = ia;
            *(float4*)(oid + (size_t)token*8 + 4) = ib;
        }
    };

    process(tok0 + p);        // token A
    process(tok0 + 32 + p);   // token B (independent pipeline; fills A's latency)
}

extern "C" void kernel_launch(void* const* d_in, const int* in_sizes, int n_in,
                              void* d_out, int out_size, void* d_ws, size_t ws_size,
                              hipStream_t stream) {
    const float* logits = (const float*)d_in[0];
    const float* bias   = (const float*)d_in[1];
    float* out = (float*)d_out;
    int T = in_sizes[0] / NEXP;        // 131072
    int nblocks = T / TPB;             // 2048
    noauxtc_router_kernel<<<nblocks, THREADS, 0, stream>>>(logits, bias, out, T);
}

// Round 6
// 197.701 us; speedup vs baseline: 1.0747x; 1.0747x over previous
//
#include <hip/hip_runtime.h>
#include <math.h>

#define THREADS 256   // 8 threads per token; thread = one expert group
#define TPB 32        // tokens per block
#define NEXP 256
// integer margins in 2^-22 quanta:
#define Q_EPS  12u    // single-score margin (~2.9e-6; pipeline err <= ~5 quanta/side)
#define QG_EPS 28u    // group-sum margin   (~6.7e-6; >= old 4e-6 float margin + quant err)

// ---- fast f32 sigmoid: hw v_exp_f32 + fast divide ----
__device__ __forceinline__ float fsigmoid(float x) {
    float e = __expf(-x);
    return __fdividef(1.0f, 1.0f + e);
}

// ---- cheap near-exact f64 sigmoid (rare paths only): Taylor exp + NR division ----
__device__ __forceinline__ double dsigmoid(float xf) {
    xf = fminf(fmaxf(xf, -500.0f), 500.0f);
    double x = (double)xf;
    double t = x * -1.4426950408889634074;           // -x*log2(e)
    double n = floor(t + 0.5);
    int ni = (int)n;
    double u = (t - n) * 0.69314718055994530942;
    double pp = 2.08767569878680990e-9;
    pp = fma(pp, u, 2.50521083854417188e-8);
    pp = fma(pp, u, 2.75573192239858907e-7);
    pp = fma(pp, u, 2.75573192239858883e-6);
    pp = fma(pp, u, 2.48015873015873016e-5);
    pp = fma(pp, u, 1.98412698412698413e-4);
    pp = fma(pp, u, 1.38888888888888889e-3);
    pp = fma(pp, u, 8.33333333333333333e-3);
    pp = fma(pp, u, 4.16666666666666667e-2);
    pp = fma(pp, u, 1.66666666666666667e-1);
    pp = fma(pp, u, 0.5);
    pp = fma(pp, u, 1.0);
    pp = fma(pp, u, 1.0);
    double sc = __longlong_as_double((long long)(1023 + ni) << 52);
    double e = pp * sc;                              // exp(-x)
    double w = 1.0 + e;
    double y = (double)__fdividef(1.0f, (float)w);
    y = fma(y, fma(-w, y, 1.0), y);
    y = fma(y, fma(-w, y, 1.0), y);
    return y;
}

// f64 8-deep sorted insert (cold path)
#define DINS(cc, ee) do {                                                \
    double _d=(cc); int _e=(ee);                                         \
    if (_d > s7) {                                                       \
        bool _b0=_d>s0,_b1=_d>s1,_b2=_d>s2,_b3=_d>s3,_b4=_d>s4,          \
             _b5=_d>s5,_b6=_d>s6;                                        \
        s7=_b6?s6:_d;           c7=_b6?c6:_e;                            \
        s6=_b5?s5:(_b6?_d:s6);  c6=_b5?c5:(_b6?_e:c6);                   \
        s5=_b4?s4:(_b5?_d:s5);  c5=_b4?c4:(_b5?_e:c5);                   \
        s4=_b3?s3:(_b4?_d:s4);  c4=_b3?c3:(_b4?_e:c4);                   \
        s3=_b2?s2:(_b3?_d:s3);  c3=_b2?c2:(_b3?_e:c3);                   \
        s2=_b1?s1:(_b2?_d:s2);  c2=_b1?c1:(_b2?_e:c2);                   \
        s1=_b0?s0:(_b1?_d:s1);  c1=_b0?c0:(_b1?_e:c1);                   \
        s0=_b0?_d:s0;           c0=_b0?_e:c0;                            \
    } } while (0)

// ======== packed sort keys (validated rounds 3-5) ========
// key = (u32(c*2^22 + 2^21) << 8) + (255 - expert_id)
// u32 desc order == (score desc, id asc) exactly; keys unique (ids unique).
// Quantum 2.38e-7; any ambiguity within Q_EPS quanta -> exact f64 re-resolve.
// Bias pre-scaled into the pack constant: Bq[e] = bias[e]*2^22 + 2^21.

// CEU: descending compare-exchange -> v_max_u32 + v_min_u32 (2 VALU)
#define CEU(a, b) do {                                                   \
    unsigned _x=(a), _y=(b);                                             \
    (a) = _x>_y ? _x : _y; (b) = _x>_y ? _y : _x;                        \
} while (0)
// VMU: a := max(a,b) -> v_max_u32 (1 VALU)
#define VMU(a, b) do { (a) = (a)>(b) ? (a) : (b); } while (0)

// Batcher odd-even mergesort network for 8 keys, descending. 19 CE.
#define SORT8U(v0,v1,v2,v3,v4,v5,v6,v7) do {                             \
    CEU(v0,v1); CEU(v2,v3); CEU(v4,v5); CEU(v6,v7);                      \
    CEU(v0,v2); CEU(v1,v3); CEU(v4,v6); CEU(v5,v7);                      \
    CEU(v1,v2); CEU(v5,v6);                                              \
    CEU(v0,v4); CEU(v1,v5); CEU(v2,v6); CEU(v3,v7);                      \
    CEU(v2,v4); CEU(v3,v5);                                              \
    CEU(v1,v2); CEU(v3,v4); CEU(v5,v6);                                  \
} while (0)

// valley (dec-then-inc) 9-seq -> sorted descending. 13 CE. (validated r1-r5)
#define CLEAN9M(a0,a1,a2,a3,a4,a5,a6,a7,a8) do {                         \
    CEU(a0,a8);                                                          \
    CEU(a1,a5); CEU(a2,a6); CEU(a3,a7); CEU(a4,a8);                      \
    CEU(a1,a3); CEU(a2,a4); CEU(a5,a7); CEU(a6,a8);                      \
    CEU(a1,a2); CEU(a3,a4); CEU(a5,a6); CEU(a7,a8);                      \
} while (0)

// Merge my sorted-desc 9-list with xor-partner's via the bitonic identity:
//   t[i] = max(a[i], b[8-i]) is the top-9 multiset, as a valley sequence.
#define XMERGE_U(d) do {                                                 \
    unsigned q0=(unsigned)__shfl_xor((int)m0,d,64),                      \
             q1=(unsigned)__shfl_xor((int)m1,d,64),                      \
             q2=(unsigned)__shfl_xor((int)m2,d,64),                      \
             q3=(unsigned)__shfl_xor((int)m3,d,64),                      \
             q4=(unsigned)__shfl_xor((int)m4,d,64),                      \
             q5=(unsigned)__shfl_xor((int)m5,d,64),                      \
             q6=(unsigned)__shfl_xor((int)m6,d,64),                      \
             q7=(unsigned)__shfl_xor((int)m7,d,64),                      \
             q8=(unsigned)__shfl_xor((int)m8,d,64);                      \
    VMU(m0,q8); VMU(m1,q7); VMU(m2,q6); VMU(m3,q5); VMU(m4,q4);          \
    VMU(m5,q3); VMU(m6,q2); VMU(m7,q1); VMU(m8,q0);                      \
    CLEAN9M(m0,m1,m2,m3,m4,m5,m6,m7,m8);                                 \
} while (0)

// (256,4): VGPR cap 128. Peak live ~75. Spill canary: WRITE_SIZE ~8.3 MB.
__global__ __launch_bounds__(THREADS, 4)
void noauxtc_router_kernel(const float* __restrict__ logits,
                           const float* __restrict__ bias,
                           float* __restrict__ out,   // [T*8] weights, [T*8] ids-as-f32
                           int T)
{
    // 32 tokens x 64 float4, xor-swizzled: element (t, c) at tile4[t*64 + (c ^ (t&7))]
    // write: full-row b128 permuted writes -> conflict-free
    // read: thread (p,h) quad q: col h*8+q, xor p&7 spreads 8 p-classes over banks
    __shared__ float4 tile4[TPB * 64];                 // 32 KiB raw logits
    __shared__ __align__(16) float bias_sh[NEXP];      // raw bias (recovery + cold)
    __shared__ __align__(16) float biasq_sh[NEXP];     // bias*2^22 + 2^21 (pack const)

    const int tid   = threadIdx.x;
    const int h     = tid & 7;            // owned group (experts 32h..32h+31)
    const int p     = tid >> 3;           // token-in-block
    const int pm    = p & 7;              // read-swizzle key
    const int tok0  = blockIdx.x * TPB;
    const int token = tok0 + p;
    const int lane  = tid & 63;
    const int base  = lane & 56;          // first lane of this token's octet

    // ---------------- coalesced stage: 1KB contiguous per instruction ----------------
    // lane-contiguous float4: 8 cache lines per instruction (vs 64 for the
    // per-thread-own-line pattern of r3-r5 -> 8x fewer TA line-requests).
    const float4* lg4 = (const float4*)logits;
    float4 stg[8];
    #pragma unroll
    for (int k = 0; k < 8; ++k)
        stg[k] = lg4[(size_t)tok0 * 64 + k * 256 + tid];

    {
        float b = bias[tid];              // THREADS == NEXP
        bias_sh[tid]  = b;
        biasq_sh[tid] = fmaf(b, 4194304.0f, 2097152.0f);
    }

    #pragma unroll
    for (int k = 0; k < 8; ++k) {
        int flat = k * 256 + tid;
        int t = flat >> 6, c = flat & 63;
        tile4[t * 64 + (c ^ (t & 7))] = stg[k];
    }
    __syncthreads();                      // only barrier

    const float4* bq4 = (const float4*)biasq_sh;

    // ---------------- pass 1: LDS-read own group's quads, sigmoid + pack keys ----------------
    unsigned kk[32];
    #pragma unroll
    for (int q = 0; q < 8; ++q) {
        float4 x = tile4[p * 64 + ((h * 8 + q) ^ pm)];   // ds_read_b128, 2-way = free
        float4 B = bq4[h * 8 + q];                        // broadcast across octets
        int idf = 255 - (h * 32 + q * 4);
        kk[q*4+0] = ((unsigned)fmaf(fsigmoid(x.x), 4194304.0f, B.x) << 8) + (unsigned)(idf    );
        kk[q*4+1] = ((unsigned)fmaf(fsigmoid(x.y), 4194304.0f, B.y) << 8) + (unsigned)(idf - 1);
        kk[q*4+2] = ((unsigned)fmaf(fsigmoid(x.z), 4194304.0f, B.z) << 8) + (unsigned)(idf - 2);
        kk[q*4+3] = ((unsigned)fmaf(fsigmoid(x.w), 4194304.0f, B.w) << 8) + (unsigned)(idf - 3);
    }

    // ---------------- own-group sorted top-9 of 32 (4x sort8 -> valleys) ----------------
    SORT8U(kk[0], kk[1], kk[2], kk[3], kk[4], kk[5], kk[6], kk[7]);
    SORT8U(kk[8], kk[9], kk[10],kk[11],kk[12],kk[13],kk[14],kk[15]);
    SORT8U(kk[16],kk[17],kk[18],kk[19],kk[20],kk[21],kk[22],kk[23]);
    SORT8U(kk[24],kk[25],kk[26],kk[27],kk[28],kk[29],kk[30],kk[31]);

    unsigned t0=kk[0],t1=kk[1],t2=kk[2],t3=kk[3],t4=kk[4],t5=kk[5],t6=kk[6],t7=kk[7],t8=0u;
    VMU(t1,kk[15]); VMU(t2,kk[14]); VMU(t3,kk[13]); VMU(t4,kk[12]);
    VMU(t5,kk[11]); VMU(t6,kk[10]); VMU(t7,kk[9]);  VMU(t8,kk[8]);
    CLEAN9M(t0,t1,t2,t3,t4,t5,t6,t7,t8);

    unsigned u0=kk[16],u1=kk[17],u2=kk[18],u3=kk[19],u4=kk[20],u5=kk[21],u6=kk[22],u7=kk[23],u8=0u;
    VMU(u1,kk[31]); VMU(u2,kk[30]); VMU(u3,kk[29]); VMU(u4,kk[28]);
    VMU(u5,kk[27]); VMU(u6,kk[26]); VMU(u7,kk[25]); VMU(u8,kk[24]);
    CLEAN9M(u0,u1,u2,u3,u4,u5,u6,u7,u8);

    unsigned m0=t0,m1=t1,m2=t2,m3=t3,m4=t4,m5=t5,m6=t6,m7=t7,m8=t8;
    VMU(m0,u8); VMU(m1,u7); VMU(m2,u6); VMU(m3,u5); VMU(m4,u4);
    VMU(m5,u3); VMU(m6,u2); VMU(m7,u1); VMU(m8,u0);
    CLEAN9M(m0,m1,m2,m3,m4,m5,m6,m7,m8);

    // ---------------- group selection: packed group keys + SORT8 ----------------
    unsigned gq   = (m0 >> 8) + (m1 >> 8);            // top-2 sum, < 2^24
    unsigned gkey = (gq << 3) + (unsigned)(7 - h);    // (score desc, group id asc)

    unsigned gk0 = (unsigned)__shfl((int)gkey, base + 0, 64);
    unsigned gk1 = (unsigned)__shfl((int)gkey, base + 1, 64);
    unsigned gk2 = (unsigned)__shfl((int)gkey, base + 2, 64);
    unsigned gk3 = (unsigned)__shfl((int)gkey, base + 3, 64);
    unsigned gk4 = (unsigned)__shfl((int)gkey, base + 4, 64);
    unsigned gk5 = (unsigned)__shfl((int)gkey, base + 5, 64);
    unsigned gk6 = (unsigned)__shfl((int)gkey, base + 6, 64);
    unsigned gk7 = (unsigned)__shfl((int)gkey, base + 7, 64);
    SORT8U(gk0,gk1,gk2,gk3,gk4,gk5,gk6,gk7);

    int selmask = (1 << ((gk0 & 7u) ^ 7u)) | (1 << ((gk1 & 7u) ^ 7u)) |
                  (1 << ((gk2 & 7u) ^ 7u)) | (1 << ((gk3 & 7u) ^ 7u));

    // ---- flagA: ambiguous 4th vs 5th group -> pure-f64 re-rank (cold; from LDS) ----
    if (__builtin_expect((gk3 >> 3) - (gk4 >> 3) < QG_EPS, 0)) {
        double a1 = -1e300, a2 = -1e300;
        #pragma unroll 1
        for (int k = 0; k < 32; ++k) {
            int e = h * 32 + k;
            const float* tf = (const float*)(tile4 + p * 64 + ((e >> 2) ^ pm));
            double c = dsigmoid(tf[e & 3]) + (double)bias_sh[e];
            a2 = fmax(a2, fmin(a1, c)); a1 = fmax(a1, c);
        }
        double gdo = a1 + a2;
        double gd[8];
        #pragma unroll
        for (int g = 0; g < 8; ++g) gd[g] = __shfl(gdo, base + g, 64);
        int sm = 0;
        #pragma unroll
        for (int a = 0; a < 8; ++a) {
            int rk = 0;
            #pragma unroll
            for (int b = 0; b < 8; ++b) {
                if (b == a) continue;
                bool beat = (b < a) ? (gd[b] >= gd[a]) : (gd[b] > gd[a]);
                rk += beat ? 1 : 0;
            }
            sm |= (rk < 4) ? (1 << a) : 0;
        }
        selmask = sm;
    }

    // ---------------- mask unselected lanes' lists (real keys >> 0) ----------------
    {
        bool sel = (selmask >> h) & 1;
        m0 = sel ? m0 : 0u; m1 = sel ? m1 : 0u; m2 = sel ? m2 : 0u;
        m3 = sel ? m3 : 0u; m4 = sel ? m4 : 0u; m5 = sel ? m5 : 0u;
        m6 = sel ? m6 : 0u; m7 = sel ? m7 : 0u; m8 = sel ? m8 : 0u;
    }

    // ---------------- butterfly bitonic merges: 8 lists of 9 -> global top-9 ----------------
    XMERGE_U(1);
    XMERGE_U(2);
    XMERGE_U(4);

    // ---------------- tail: only the h==0 lane of each octet pays ----------------
    if (h == 0) {
        unsigned q0=m0>>8, q1=m1>>8, q2=m2>>8, q3=m3>>8, q4=m4>>8,
                 q5=m5>>8, q6=m6>>8, q7=m7>>8, q8=m8>>8;
        int n0=255-(int)(m0&255u), n1=255-(int)(m1&255u), n2=255-(int)(m2&255u),
            n3=255-(int)(m3&255u), n4=255-(int)(m4&255u), n5=255-(int)(m5&255u),
            n6=255-(int)(m6&255u), n7=255-(int)(m7&255u), n8=255-(int)(m8&255u);

        float bn0=bias_sh[n0], bn1=bias_sh[n1], bn2=bias_sh[n2], bn3=bias_sh[n3],
              bn4=bias_sh[n4], bn5=bias_sh[n5], bn6=bias_sh[n6], bn7=bias_sh[n7];

        const float QS = 2.384185791015625e-7f;  // 2^-22
        float w0=fmaf((float)q0,QS,-0.5f)-bn0, w1=fmaf((float)q1,QS,-0.5f)-bn1,
              w2=fmaf((float)q2,QS,-0.5f)-bn2, w3=fmaf((float)q3,QS,-0.5f)-bn3,
              w4=fmaf((float)q4,QS,-0.5f)-bn4, w5=fmaf((float)q5,QS,-0.5f)-bn5,
              w6=fmaf((float)q6,QS,-0.5f)-bn6, w7=fmaf((float)q7,QS,-0.5f)-bn7;
        int o0=n0,o1=n1,o2=n2,o3=n3,o4=n4,o5=n5,o6=n6,o7=n7;

        // q-list non-increasing -> unsigned diffs safe
        bool flagB = ((q0-q1<Q_EPS)|(q1-q2<Q_EPS)|(q2-q3<Q_EPS)|(q3-q4<Q_EPS)|
                      (q4-q5<Q_EPS)|(q5-q6<Q_EPS)|(q6-q7<Q_EPS)|(q7-q8<Q_EPS));
        if (__builtin_expect(flagB, 0)) {
            // f64 re-resolve of the 9 f32-top candidates; logits from LDS (cold)
            double s0=-1e300,s1=-1e300,s2=-1e300,s3=-1e300,
                   s4=-1e300,s5=-1e300,s6=-1e300,s7=-1e300;
            int c0=0,c1=0,c2=0,c3=0,c4=0,c5=0,c6=0,c7=0;
            int ci[9] = {n0,n1,n2,n3,n4,n5,n6,n7,n8};
            #pragma unroll 1
            for (int k = 0; k < 9; ++k) {
                int e = ci[k];
                const float* tf = (const float*)(tile4 + p * 64 + ((e >> 2) ^ pm));
                double cs = dsigmoid(tf[e & 3]) + (double)bias_sh[e];
                DINS(cs, e);
            }
            w0=(float)(s0-(double)bias_sh[c0]); o0=c0;
            w1=(float)(s1-(double)bias_sh[c1]); o1=c1;
            w2=(float)(s2-(double)bias_sh[c2]); o2=c2;
            w3=(float)(s3-(double)bias_sh[c3]); o3=c3;
            w4=(float)(s4-(double)bias_sh[c4]); o4=c4;
            w5=(float)(s5-(double)bias_sh[c5]); o5=c5;
            w6=(float)(s6-(double)bias_sh[c6]); o6=c6;
            w7=(float)(s7-(double)bias_sh[c7]); o7=c7;
        }

        // epilogue
        float sum = ((w0+w1)+(w2+w3)) + ((w4+w5)+(w6+w7));
        float scl = 2.5f / (sum + 1e-20f);
        float4 oa, ob;
        oa.x=w0*scl; oa.y=w1*scl; oa.z=w2*scl; oa.w=w3*scl;
        ob.x=w4*scl; ob.y=w5*scl; ob.z=w6*scl; ob.w=w7*scl;
        *(float4*)(out + (size_t)token*8)     = oa;
        *(float4*)(out + (size_t)token*8 + 4) = ob;
        float* oid = out + (size_t)T*8;
        float4 ia, ib;
        ia.x=(float)o0; ia.y=(float)o1; ia.z=(float)o2; ia.w=(float)o3;
        ib.x=(float)o4; ib.y=(float)o5; ib.z=(float)o6; ib.w=(float)o7;
        *(float4*)(oid + (size_t)token*8)     = ia;
        *(float4*)(oid + (size_t)token*8 + 4) = ib;
    }
}

extern "C" void kernel_launch(void* const* d_in, const int* in_sizes, int n_in,
                              void* d_out, int out_size, void* d_ws, size_t ws_size,
                              hipStream_t stream) {
    const float* logits = (const float*)d_in[0];
    const float* bias   = (const float*)d_in[1];
    float* out = (float*)d_out;
    int T = in_sizes[0] / NEXP;        // 131072
    int nblocks = T / TPB;             // 4096
    noauxtc_router_kernel<<<nblocks, THREADS, 0, stream>>>(logits, bias, out, T);
}

// Round 7
// 196.333 us; speedup vs baseline: 1.0822x; 1.0070x over previous
//
#include <hip/hip_runtime.h>
#include <math.h>

#define THREADS 256   // 8 threads per token; thread = one expert group (sort phase)
#define TPB 32        // tokens per block
#define NEXP 256
// integer margins in 2^-22 quanta:
#define Q_EPS  12u    // single-score margin (~2.9e-6; pipeline err <= ~5 quanta/side)
#define QG_EPS 28u    // group-sum margin   (~6.7e-6; >= old 4e-6 float margin + quant err)

// ---- fast f32 sigmoid: hw v_exp_f32 + fast divide ----
__device__ __forceinline__ float fsigmoid(float x) {
    float e = __expf(-x);
    return __fdividef(1.0f, 1.0f + e);
}

// ---- cheap near-exact f64 sigmoid (rare paths only): Taylor exp + NR division ----
__device__ __forceinline__ double dsigmoid(float xf) {
    xf = fminf(fmaxf(xf, -500.0f), 500.0f);
    double x = (double)xf;
    double t = x * -1.4426950408889634074;           // -x*log2(e)
    double n = floor(t + 0.5);
    int ni = (int)n;
    double u = (t - n) * 0.69314718055994530942;
    double pp = 2.08767569878680990e-9;
    pp = fma(pp, u, 2.50521083854417188e-8);
    pp = fma(pp, u, 2.75573192239858907e-7);
    pp = fma(pp, u, 2.75573192239858883e-6);
    pp = fma(pp, u, 2.48015873015873016e-5);
    pp = fma(pp, u, 1.98412698412698413e-4);
    pp = fma(pp, u, 1.38888888888888889e-3);
    pp = fma(pp, u, 8.33333333333333333e-3);
    pp = fma(pp, u, 4.16666666666666667e-2);
    pp = fma(pp, u, 1.66666666666666667e-1);
    pp = fma(pp, u, 0.5);
    pp = fma(pp, u, 1.0);
    pp = fma(pp, u, 1.0);
    double sc = __longlong_as_double((long long)(1023 + ni) << 52);
    double e = pp * sc;                              // exp(-x)
    double w = 1.0 + e;
    double y = (double)__fdividef(1.0f, (float)w);
    y = fma(y, fma(-w, y, 1.0), y);
    y = fma(y, fma(-w, y, 1.0), y);
    return y;
}

// f64 8-deep sorted insert (cold path)
#define DINS(cc, ee) do {                                                \
    double _d=(cc); int _e=(ee);                                         \
    if (_d > s7) {                                                       \
        bool _b0=_d>s0,_b1=_d>s1,_b2=_d>s2,_b3=_d>s3,_b4=_d>s4,          \
             _b5=_d>s5,_b6=_d>s6;                                        \
        s7=_b6?s6:_d;           c7=_b6?c6:_e;                            \
        s6=_b5?s5:(_b6?_d:s6);  c6=_b5?c5:(_b6?_e:c6);                   \
        s5=_b4?s4:(_b5?_d:s5);  c5=_b4?c4:(_b5?_e:c5);                   \
        s4=_b3?s3:(_b4?_d:s4);  c4=_b3?c3:(_b4?_e:c4);                   \
        s3=_b2?s2:(_b3?_d:s3);  c3=_b2?c2:(_b3?_e:c3);                   \
        s2=_b1?s1:(_b2?_d:s2);  c2=_b1?c1:(_b2?_e:c2);                   \
        s1=_b0?s0:(_b1?_d:s1);  c1=_b0?c0:(_b1?_e:c1);                   \
        s0=_b0?_d:s0;           c0=_b0?_e:c0;                            \
    } } while (0)

// ======== packed sort keys (validated rounds 3-6) ========
// key = (u32(c*2^22 + 2^21) << 8) + (255 - expert_id)
// u32 desc order == (score desc, id asc) exactly; keys unique (ids unique).
// Quantum 2.38e-7; any ambiguity within Q_EPS quanta -> exact f64 re-resolve.
// Bias pre-scaled into the pack constant: Bq[e] = bias[e]*2^22 + 2^21.
// Keys are bit-identical regardless of which thread computes them, so the
// pre-transpose pack (this round) produces the same keys as rounds 3-6.

// CEU: descending compare-exchange -> v_max_u32 + v_min_u32 (2 VALU)
#define CEU(a, b) do {                                                   \
    unsigned _x=(a), _y=(b);                                             \
    (a) = _x>_y ? _x : _y; (b) = _x>_y ? _y : _x;                        \
} while (0)
// VMU: a := max(a,b) -> v_max_u32 (1 VALU)
#define VMU(a, b) do { (a) = (a)>(b) ? (a) : (b); } while (0)

// Batcher odd-even mergesort network for 8 keys, descending. 19 CE.
#define SORT8U(v0,v1,v2,v3,v4,v5,v6,v7) do {                             \
    CEU(v0,v1); CEU(v2,v3); CEU(v4,v5); CEU(v6,v7);                      \
    CEU(v0,v2); CEU(v1,v3); CEU(v4,v6); CEU(v5,v7);                      \
    CEU(v1,v2); CEU(v5,v6);                                              \
    CEU(v0,v4); CEU(v1,v5); CEU(v2,v6); CEU(v3,v7);                      \
    CEU(v2,v4); CEU(v3,v5);                                              \
    CEU(v1,v2); CEU(v3,v4); CEU(v5,v6);                                  \
} while (0)

// valley (dec-then-inc) 9-seq -> sorted descending. 13 CE. (validated r1-r6)
#define CLEAN9M(a0,a1,a2,a3,a4,a5,a6,a7,a8) do {                         \
    CEU(a0,a8);                                                          \
    CEU(a1,a5); CEU(a2,a6); CEU(a3,a7); CEU(a4,a8);                      \
    CEU(a1,a3); CEU(a2,a4); CEU(a5,a7); CEU(a6,a8);                      \
    CEU(a1,a2); CEU(a3,a4); CEU(a5,a6); CEU(a7,a8);                      \
} while (0)

// Merge my sorted-desc 9-list with xor-partner's via the bitonic identity:
//   t[i] = max(a[i], b[8-i]) is the top-9 multiset, as a valley sequence.
#define XMERGE_U(d) do {                                                 \
    unsigned q0=(unsigned)__shfl_xor((int)m0,d,64),                      \
             q1=(unsigned)__shfl_xor((int)m1,d,64),                      \
             q2=(unsigned)__shfl_xor((int)m2,d,64),                      \
             q3=(unsigned)__shfl_xor((int)m3,d,64),                      \
             q4=(unsigned)__shfl_xor((int)m4,d,64),                      \
             q5=(unsigned)__shfl_xor((int)m5,d,64),                      \
             q6=(unsigned)__shfl_xor((int)m6,d,64),                      \
             q7=(unsigned)__shfl_xor((int)m7,d,64),                      \
             q8=(unsigned)__shfl_xor((int)m8,d,64);                      \
    VMU(m0,q8); VMU(m1,q7); VMU(m2,q6); VMU(m3,q5); VMU(m4,q4);          \
    VMU(m5,q3); VMU(m6,q2); VMU(m7,q1); VMU(m8,q0);                      \
    CLEAN9M(m0,m1,m2,m3,m4,m5,m6,m7,m8);                                 \
} while (0)

// (256,4): VGPR cap 128. Peak live ~75. Spill canary: WRITE_SIZE ~8.3 MB.
__global__ __launch_bounds__(THREADS, 4)
void noauxtc_router_kernel(const float* __restrict__ logits,
                           const float* __restrict__ bias,
                           float* __restrict__ out,   // [T*8] weights, [T*8] ids-as-f32
                           int T)
{
    // key tile: 32 tokens x 64 uint4, xor-swizzled [t][c ^ (t&7)] (r0/r6 scheme):
    // write: per wave t is constant, c=0..63 distinct -> b128 permuted rows, conflict-free
    // read: thread (p,h) quad q: col h*8+q, xor p&7 spreads p-classes over banks (2-way, free)
    __shared__ uint4 ktile[TPB * 64];                  // 32 KiB packed keys
    __shared__ __align__(16) float bias_sh[NEXP];      // raw bias (tail recovery + cold)

    const int tid   = threadIdx.x;
    const int h     = tid & 7;            // owned group (experts 32h..32h+31)
    const int p     = tid >> 3;           // token-in-block
    const int pm    = p & 7;              // read-swizzle key
    const int tok0  = blockIdx.x * TPB;
    const int token = tok0 + p;
    const int lane  = tid & 63;
    const int base  = lane & 56;          // first lane of this token's octet

    // ---------------- coalesced loads: 1KB contiguous per instruction ----------------
    const float4* lg4 = (const float4*)logits;
    float4 stg[8];
    #pragma unroll
    for (int k = 0; k < 8; ++k)
        stg[k] = lg4[(size_t)tok0 * 64 + k * 256 + tid];

    // my loaded column is the same for all 8 loads: (k*256+tid) & 63 == tid & 63.
    // -> one float4 of bias pack-constants covers every element this thread packs.
    const int col = tid & 63;                          // float4-column within token
    float4 bb = ((const float4*)bias)[col];            // experts 4col..4col+3 (coalesced)
    bias_sh[tid] = bias[tid];                          // raw bias for tail/cold (THREADS==NEXP)

    float4 Bq;                                         // bias*2^22 + 2^21
    Bq.x = fmaf(bb.x, 4194304.0f, 2097152.0f);
    Bq.y = fmaf(bb.y, 4194304.0f, 2097152.0f);
    Bq.z = fmaf(bb.z, 4194304.0f, 2097152.0f);
    Bq.w = fmaf(bb.w, 4194304.0f, 2097152.0f);

    // ---------------- pack DURING load latency: sigmoid+quantize pre-transpose --------
    // elementwise -> thread assignment irrelevant; keys bit-identical to r3-r6.
    const unsigned idf  = 255u - (unsigned)(col * 4);  // idflip for elem .x
    const int      trow = tid >> 6;                    // wave id: token t = k*4 + trow
    #pragma unroll
    for (int k = 0; k < 8; ++k) {
        uint4 kv;
        kv.x = ((unsigned)fmaf(fsigmoid(stg[k].x), 4194304.0f, Bq.x) << 8) + (idf    );
        kv.y = ((unsigned)fmaf(fsigmoid(stg[k].y), 4194304.0f, Bq.y) << 8) + (idf - 1u);
        kv.z = ((unsigned)fmaf(fsigmoid(stg[k].z), 4194304.0f, Bq.z) << 8) + (idf - 2u);
        kv.w = ((unsigned)fmaf(fsigmoid(stg[k].w), 4194304.0f, Bq.w) << 8) + (idf - 3u);
        int t = k * 4 + trow;
        ktile[t * 64 + (col ^ (t & 7))] = kv;
    }
    __syncthreads();                      // only barrier

    // ---------------- sort phase: read own group's 32 keys from LDS ----------------
    unsigned kk[32];
    #pragma unroll
    for (int q = 0; q < 8; ++q) {
        uint4 kv = ktile[p * 64 + ((h * 8 + q) ^ pm)];   // ds_read_b128, 2-way = free
        kk[q*4+0] = kv.x; kk[q*4+1] = kv.y; kk[q*4+2] = kv.z; kk[q*4+3] = kv.w;
    }

    // ---------------- own-group sorted top-9 of 32 (4x sort8 -> valleys) ----------------
    SORT8U(kk[0], kk[1], kk[2], kk[3], kk[4], kk[5], kk[6], kk[7]);
    SORT8U(kk[8], kk[9], kk[10],kk[11],kk[12],kk[13],kk[14],kk[15]);
    SORT8U(kk[16],kk[17],kk[18],kk[19],kk[20],kk[21],kk[22],kk[23]);
    SORT8U(kk[24],kk[25],kk[26],kk[27],kk[28],kk[29],kk[30],kk[31]);

    unsigned t0=kk[0],t1=kk[1],t2=kk[2],t3=kk[3],t4=kk[4],t5=kk[5],t6=kk[6],t7=kk[7],t8=0u;
    VMU(t1,kk[15]); VMU(t2,kk[14]); VMU(t3,kk[13]); VMU(t4,kk[12]);
    VMU(t5,kk[11]); VMU(t6,kk[10]); VMU(t7,kk[9]);  VMU(t8,kk[8]);
    CLEAN9M(t0,t1,t2,t3,t4,t5,t6,t7,t8);

    unsigned u0=kk[16],u1=kk[17],u2=kk[18],u3=kk[19],u4=kk[20],u5=kk[21],u6=kk[22],u7=kk[23],u8=0u;
    VMU(u1,kk[31]); VMU(u2,kk[30]); VMU(u3,kk[29]); VMU(u4,kk[28]);
    VMU(u5,kk[27]); VMU(u6,kk[26]); VMU(u7,kk[25]); VMU(u8,kk[24]);
    CLEAN9M(u0,u1,u2,u3,u4,u5,u6,u7,u8);

    unsigned m0=t0,m1=t1,m2=t2,m3=t3,m4=t4,m5=t5,m6=t6,m7=t7,m8=t8;
    VMU(m0,u8); VMU(m1,u7); VMU(m2,u6); VMU(m3,u5); VMU(m4,u4);
    VMU(m5,u3); VMU(m6,u2); VMU(m7,u1); VMU(m8,u0);
    CLEAN9M(m0,m1,m2,m3,m4,m5,m6,m7,m8);

    // ---------------- group selection: packed group keys + SORT8 ----------------
    unsigned gq   = (m0 >> 8) + (m1 >> 8);            // top-2 sum, < 2^24
    unsigned gkey = (gq << 3) + (unsigned)(7 - h);    // (score desc, group id asc)

    unsigned gk0 = (unsigned)__shfl((int)gkey, base + 0, 64);
    unsigned gk1 = (unsigned)__shfl((int)gkey, base + 1, 64);
    unsigned gk2 = (unsigned)__shfl((int)gkey, base + 2, 64);
    unsigned gk3 = (unsigned)__shfl((int)gkey, base + 3, 64);
    unsigned gk4 = (unsigned)__shfl((int)gkey, base + 4, 64);
    unsigned gk5 = (unsigned)__shfl((int)gkey, base + 5, 64);
    unsigned gk6 = (unsigned)__shfl((int)gkey, base + 6, 64);
    unsigned gk7 = (unsigned)__shfl((int)gkey, base + 7, 64);
    SORT8U(gk0,gk1,gk2,gk3,gk4,gk5,gk6,gk7);

    int selmask = (1 << ((gk0 & 7u) ^ 7u)) | (1 << ((gk1 & 7u) ^ 7u)) |
                  (1 << ((gk2 & 7u) ^ 7u)) | (1 << ((gk3 & 7u) ^ 7u));

    // ---- flagA: ambiguous 4th vs 5th group -> pure-f64 re-rank (cold; global) ----
    if (__builtin_expect((gk3 >> 3) - (gk4 >> 3) < QG_EPS, 0)) {
        double a1 = -1e300, a2 = -1e300;
        const float* lgp = logits + (size_t)token * 256 + h * 32;
        #pragma unroll 1
        for (int k = 0; k < 32; ++k) {
            double c = dsigmoid(lgp[k]) + (double)bias_sh[h * 32 + k];
            a2 = fmax(a2, fmin(a1, c)); a1 = fmax(a1, c);
        }
        double gdo = a1 + a2;
        double gd[8];
        #pragma unroll
        for (int g = 0; g < 8; ++g) gd[g] = __shfl(gdo, base + g, 64);
        int sm = 0;
        #pragma unroll
        for (int a = 0; a < 8; ++a) {
            int rk = 0;
            #pragma unroll
            for (int b = 0; b < 8; ++b) {
                if (b == a) continue;
                bool beat = (b < a) ? (gd[b] >= gd[a]) : (gd[b] > gd[a]);
                rk += beat ? 1 : 0;
            }
            sm |= (rk < 4) ? (1 << a) : 0;
        }
        selmask = sm;
    }

    // ---------------- mask unselected lanes' lists (real keys >> 0) ----------------
    {
        bool sel = (selmask >> h) & 1;
        m0 = sel ? m0 : 0u; m1 = sel ? m1 : 0u; m2 = sel ? m2 : 0u;
        m3 = sel ? m3 : 0u; m4 = sel ? m4 : 0u; m5 = sel ? m5 : 0u;
        m6 = sel ? m6 : 0u; m7 = sel ? m7 : 0u; m8 = sel ? m8 : 0u;
    }

    // ---------------- butterfly bitonic merges: 8 lists of 9 -> global top-9 ----------------
    XMERGE_U(1);
    XMERGE_U(2);
    XMERGE_U(4);

    // ---------------- tail: only the h==0 lane of each octet pays ----------------
    if (h == 0) {
        unsigned q0=m0>>8, q1=m1>>8, q2=m2>>8, q3=m3>>8, q4=m4>>8,
                 q5=m5>>8, q6=m6>>8, q7=m7>>8, q8=m8>>8;
        int n0=255-(int)(m0&255u), n1=255-(int)(m1&255u), n2=255-(int)(m2&255u),
            n3=255-(int)(m3&255u), n4=255-(int)(m4&255u), n5=255-(int)(m5&255u),
            n6=255-(int)(m6&255u), n7=255-(int)(m7&255u), n8=255-(int)(m8&255u);

        float bn0=bias_sh[n0], bn1=bias_sh[n1], bn2=bias_sh[n2], bn3=bias_sh[n3],
              bn4=bias_sh[n4], bn5=bias_sh[n5], bn6=bias_sh[n6], bn7=bias_sh[n7];

        const float QS = 2.384185791015625e-7f;  // 2^-22
        float w0=fmaf((float)q0,QS,-0.5f)-bn0, w1=fmaf((float)q1,QS,-0.5f)-bn1,
              w2=fmaf((float)q2,QS,-0.5f)-bn2, w3=fmaf((float)q3,QS,-0.5f)-bn3,
              w4=fmaf((float)q4,QS,-0.5f)-bn4, w5=fmaf((float)q5,QS,-0.5f)-bn5,
              w6=fmaf((float)q6,QS,-0.5f)-bn6, w7=fmaf((float)q7,QS,-0.5f)-bn7;
        int o0=n0,o1=n1,o2=n2,o3=n3,o4=n4,o5=n5,o6=n6,o7=n7;

        // q-list non-increasing -> unsigned diffs safe
        bool flagB = ((q0-q1<Q_EPS)|(q1-q2<Q_EPS)|(q2-q3<Q_EPS)|(q3-q4<Q_EPS)|
                      (q4-q5<Q_EPS)|(q5-q6<Q_EPS)|(q6-q7<Q_EPS)|(q7-q8<Q_EPS));
        if (__builtin_expect(flagB, 0)) {
            // f64 re-resolve of the 9 f32-top candidates; logits from global (cold)
            double s0=-1e300,s1=-1e300,s2=-1e300,s3=-1e300,
                   s4=-1e300,s5=-1e300,s6=-1e300,s7=-1e300;
            int c0=0,c1=0,c2=0,c3=0,c4=0,c5=0,c6=0,c7=0;
            int ci[9] = {n0,n1,n2,n3,n4,n5,n6,n7,n8};
            const float* lgt = logits + (size_t)token * 256;
            #pragma unroll 1
            for (int k = 0; k < 9; ++k) {
                int e = ci[k];
                double cs = dsigmoid(lgt[e]) + (double)bias_sh[e];
                DINS(cs, e);
            }
            w0=(float)(s0-(double)bias_sh[c0]); o0=c0;
            w1=(float)(s1-(double)bias_sh[c1]); o1=c1;
            w2=(float)(s2-(double)bias_sh[c2]); o2=c2;
            w3=(float)(s3-(double)bias_sh[c3]); o3=c3;
            w4=(float)(s4-(double)bias_sh[c4]); o4=c4;
            w5=(float)(s5-(double)bias_sh[c5]); o5=c5;
            w6=(float)(s6-(double)bias_sh[c6]); o6=c6;
            w7=(float)(s7-(double)bias_sh[c7]); o7=c7;
        }

        // epilogue
        float sum = ((w0+w1)+(w2+w3)) + ((w4+w5)+(w6+w7));
        float scl = 2.5f / (sum + 1e-20f);
        float4 oa, ob;
        oa.x=w0*scl; oa.y=w1*scl; oa.z=w2*scl; oa.w=w3*scl;
        ob.x=w4*scl; ob.y=w5*scl; ob.z=w6*scl; ob.w=w7*scl;
        *(float4*)(out + (size_t)token*8)     = oa;
        *(float4*)(out + (size_t)token*8 + 4) = ob;
        float* oid = out + (size_t)T*8;
        float4 ia, ib;
        ia.x=(float)o0; ia.y=(float)o1; ia.z=(float)o2; ia.w=(float)o3;
        ib.x=(float)o4; ib.y=(float)o5; ib.z=(float)o6; ib.w=(float)o7;
        *(float4*)(oid + (size_t)token*8)     = ia;
        *(float4*)(oid + (size_t)token*8 + 4) = ib;
    }
}

extern "C" void kernel_launch(void* const* d_in, const int* in_sizes, int n_in,
                              void* d_out, int out_size, void* d_ws, size_t ws_size,
                              hipStream_t stream) {
    const float* logits = (const float*)d_in[0];
    const float* bias   = (const float*)d_in[1];
    float* out = (float*)d_out;
    int T = in_sizes[0] / NEXP;        // 131072
    int nblocks = T / TPB;             // 4096
    noauxtc_router_kernel<<<nblocks, THREADS, 0, stream>>>(logits, bias, out, T);
}